// Round 3
// baseline (1116.839 us; speedup 1.0000x reference)
//
#include <hip/hip_runtime.h>
#include <hip/hip_bf16.h>
#include <cstdint>
#include <cstddef>

// output regions (f32 elements)
#define OFF_CE 131072ull                 // c_emb [B,C,E]
#define OFF_MU (131072ull + 16777216ull) // mu
#define OFF_LV (131072ull + 33554432ull) // logvar

using bf16x8 = __attribute__((ext_vector_type(8))) __bf16;
using s16x8  = __attribute__((ext_vector_type(8))) short;
using f32x4  = __attribute__((ext_vector_type(4))) float;

__device__ __forceinline__ unsigned short f2bf(float x) {
  unsigned u = __builtin_bit_cast(unsigned, x);
  return (unsigned short)((u + 0x7FFFu + ((u >> 16) & 1u)) >> 16);
}
__device__ __forceinline__ float bf2f(unsigned short h) {
  unsigned u = ((unsigned)h) << 16;
  return __builtin_bit_cast(float, u);
}
__device__ __forceinline__ void async16(const void* g, void* l) {
  __builtin_amdgcn_global_load_lds(
      (const __attribute__((address_space(1))) void*)g,
      (__attribute__((address_space(3))) void*)l, 16, 0, 0);
}

// ---------------- converters / prep ----------------

__global__ __launch_bounds__(256) void convert_x_k(const float* __restrict__ x,
                                                   unsigned short* __restrict__ xb) {
  int idx = blockIdx.x * 256 + threadIdx.x;
  const float4* xv = (const float4*)x;
  float4 a = xv[idx * 2], b = xv[idx * 2 + 1];
  unsigned w0 = f2bf(a.x) | ((unsigned)f2bf(a.y) << 16);
  unsigned w1 = f2bf(a.z) | ((unsigned)f2bf(a.w) << 16);
  unsigned w2 = f2bf(b.x) | ((unsigned)f2bf(b.y) << 16);
  unsigned w3 = f2bf(b.z) | ((unsigned)f2bf(b.w) << 16);
  ((uint4*)xb)[idx] = make_uint4(w0, w1, w2, w3);
}

__global__ void transpose_w1_k(const float* __restrict__ src0, unsigned short* __restrict__ dst0) {
  __shared__ float t[32][33];
  const int c = blockIdx.z;
  const int k0 = blockIdx.x << 5, n0 = blockIdx.y << 5;
  const int tx = threadIdx.x, ty = threadIdx.y;
  const float* src = src0 + ((size_t)c << 20);
#pragma unroll
  for (int r = 0; r < 4; ++r)
    t[ty + (r << 3)][tx] = src[((size_t)(k0 + ty + (r << 3)) << 10) + n0 + tx];
  __syncthreads();
  unsigned short* dst = dst0 + ((size_t)c << 20);
#pragma unroll
  for (int r = 0; r < 4; ++r)
    dst[((size_t)(n0 + ty + (r << 3)) << 10) + k0 + tx] = f2bf(t[tx][ty + (r << 3)]);
}

// Wl [C,1025,1025] f32 -> WlT [C,1024(n),1024(k)] bf16 (row k=1024 and col n=1024 handled separately)
__global__ void transpose_wl_k(const float* __restrict__ Wl, unsigned short* __restrict__ WlT) {
  __shared__ float t[32][33];
  const int c = blockIdx.z;
  const int k0 = blockIdx.x << 5, n0 = blockIdx.y << 5;
  const int tx = threadIdx.x, ty = threadIdx.y;
  const float* src = Wl + (size_t)c * 1025 * 1025;
#pragma unroll
  for (int r = 0; r < 4; ++r)
    t[ty + (r << 3)][tx] = src[(size_t)(k0 + ty + (r << 3)) * 1025 + n0 + tx];
  __syncthreads();
  unsigned short* dst = WlT + ((size_t)c << 20);
#pragma unroll
  for (int r = 0; r < 4; ++r)
    dst[((size_t)(n0 + ty + (r << 3)) << 10) + k0 + tx] = f2bf(t[tx][ty + (r << 3)]);
}

// wlast[c][j]=Wl[c][1024][j], blp[c][j]=bl[c][j] (j<1024), Wlcol[c][k]=Wl[c][k][1024],
// w2l[c]=Wl[c][1024][1024], bl1024[c]=bl[c][1024]
__global__ __launch_bounds__(256) void prep_wl_k(const float* __restrict__ Wl,
                                                 const float* __restrict__ bl,
                                                 float* __restrict__ wlastf,
                                                 float* __restrict__ blpf,
                                                 float* __restrict__ Wlcolf,
                                                 float* __restrict__ w2l,
                                                 float* __restrict__ bl1024) {
  int idx = blockIdx.x * 256 + threadIdx.x;  // C*1024 = 65536
  int c = idx >> 10, j = idx & 1023;
  const float* src = Wl + (size_t)c * 1025 * 1025;
  wlastf[idx] = src[(size_t)1024 * 1025 + j];
  blpf[idx]   = bl[(size_t)c * 1025 + j];
  Wlcolf[idx] = src[(size_t)j * 1025 + 1024];
  if (j == 0) {
    w2l[c]    = src[(size_t)1024 * 1025 + 1024];
    bl1024[c] = bl[(size_t)c * 1025 + 1024];
  }
}

// WheadT [256(n),1024(k)] bf16 ; whead1024[256] f32 = row k=1024
__global__ __launch_bounds__(256) void convert_whead_k(const float* __restrict__ Wmu,
                                                       const float* __restrict__ Wlv,
                                                       unsigned short* __restrict__ WheadT,
                                                       float* __restrict__ whead1024f) {
  int idx = blockIdx.x * 256 + threadIdx.x;  // 256*1024 = 262144
  int rr = idx >> 10, k = idx & 1023;
  float v = (rr < 128) ? Wmu[(size_t)k * 128 + rr] : Wlv[(size_t)k * 128 + (rr - 128)];
  WheadT[idx] = f2bf(v);
  if (blockIdx.x == 0 && threadIdx.x < 256) {
    int r2 = threadIdx.x;
    whead1024f[r2] = (r2 < 128) ? Wmu[(size_t)1024 * 128 + r2] : Wlv[(size_t)1024 * 128 + (r2 - 128)];
  }
}

// presum[c][b] = x_b . Wlcol[c]   (f32)
__global__ __launch_bounds__(256) void colgemv_k(const unsigned short* __restrict__ xb,
                                                 const float* __restrict__ Wlcolf,
                                                 float* __restrict__ presum) {
  __shared__ unsigned short xt[32 * 1024];  // 64 KB
  const int r0 = blockIdx.x << 5;  // 64 blocks x 32 rows
  const int tid = threadIdx.x;
#pragma unroll
  for (int i = 0; i < 16; ++i)
    ((uint4*)xt)[tid * 16 + i] = ((const uint4*)(xb + (size_t)r0 * 1024))[tid * 16 + i];
  __syncthreads();
  const int wv = tid >> 6, lane = tid & 63;
  for (int c = 0; c < 64; ++c) {
    float4 w[4];
#pragma unroll
    for (int q = 0; q < 4; ++q)
      w[q] = *(const float4*)(Wlcolf + (c << 10) + lane * 16 + q * 4);
#pragma unroll
    for (int rr = 0; rr < 8; ++rr) {
      const int r = (wv << 3) + rr;
      const unsigned short* xr = xt + (r << 10) + lane * 16;
      s16x8 h0 = *(const s16x8*)xr;
      s16x8 h1 = *(const s16x8*)(xr + 8);
      float s = 0.f;
#pragma unroll
      for (int i = 0; i < 8; ++i) {
        s += bf2f((unsigned short)h0[i]) * ((const float*)&w[i >> 2])[i & 3];
        s += bf2f((unsigned short)h1[i]) * ((const float*)&w[2 + (i >> 2)])[i & 3];
      }
#pragma unroll
      for (int off = 32; off; off >>= 1) s += __shfl_xor(s, off);
      if (lane == 0) presum[(c << 11) + r0 + r] = s;
    }
  }
}

// c_pred = sigmoid(sum of spart + b2); e1024 = relu(presum + p*w2l + bl1024)
__global__ __launch_bounds__(256) void sigmoid_k(const float* __restrict__ spart,
                                                 const float* __restrict__ b2,
                                                 const float* __restrict__ presum,
                                                 const float* __restrict__ w2l,
                                                 const float* __restrict__ bl1024,
                                                 float* __restrict__ pred_out,
                                                 float* __restrict__ cpf,
                                                 float* __restrict__ e1024f) {
  int idx = blockIdx.x * 256 + threadIdx.x;  // B*C = 131072
  int b = idx >> 6, c = idx & 63;
  float s = b2[c];
#pragma unroll
  for (int q = 0; q < 4; ++q) s += spart[(((size_t)(q << 6) + c) << 11) + b];
  float p = 1.f / (1.f + expf(-s));
  pred_out[idx] = p;
  cpf[idx] = p;
  e1024f[(c << 11) + b] = fmaxf(presum[(c << 11) + b] + p * w2l[c] + bl1024[c], 0.f);
}

// ---------------- 256x256 8-phase MFMA GEMM ----------------
// MODE 0: h-tile + fused scorer partials -> ofl=spart[4][C][B]   K=1024
// MODE 1: emb = relu(acc + cp*wlast + blp) -> obf [C][B][1024]   K=1024
// MODE 2: mu/lv/ce = acc + bias + e1024*whead1024 -> d_out       K=1024

#define BAR() __builtin_amdgcn_s_barrier()
#define LGKM0() do { asm volatile("s_waitcnt lgkmcnt(0)" ::: "memory"); \
                     __builtin_amdgcn_sched_barrier(0); } while (0)
#define VM4() asm volatile("s_waitcnt vmcnt(4)" ::: "memory")
#define VM0() asm volatile("s_waitcnt vmcnt(0)" ::: "memory")

#define STAGEA(h, tt, bidx) do { _Pragma("unroll") for (int q_ = 0; q_ < 2; ++q_) \
  async16(Asrc[q_] + ((size_t)(h) * 128) * K + (size_t)(tt) * 64, \
          &sA[bidx][(h) * 8192 + chnk[q_]]); } while (0)
#define STAGEB(h, tt, bidx) do { _Pragma("unroll") for (int q_ = 0; q_ < 2; ++q_) \
  async16(Bsrc[q_] + ((size_t)(h) * 128) * K + (size_t)(tt) * 64, \
          &sB[bidx][(h) * 8192 + chnk[q_]]); } while (0)

#define LOADA(mh, bidx) do { _Pragma("unroll") for (int i_ = 0; i_ < 4; ++i_) { \
  const int ro_ = ((mh) * 128 + wm64 + i_ * 16 + l15) << 6; \
  a[i_][0] = *(const bf16x8*)&sA[bidx][ro_ + ccx0]; \
  a[i_][1] = *(const bf16x8*)&sA[bidx][ro_ + ccx1]; } } while (0)

#define LOADB(nh, bb, bidx) do { _Pragma("unroll") for (int j_ = 0; j_ < 2; ++j_) { \
  const int ro_ = ((nh) * 128 + wn32 + j_ * 16 + l15) << 6; \
  bb[j_][0] = *(const bf16x8*)&sB[bidx][ro_ + ccx0]; \
  bb[j_][1] = *(const bf16x8*)&sB[bidx][ro_ + ccx1]; } } while (0)

#define MMAQ(mh, nh, bb) do { _Pragma("unroll") for (int i_ = 0; i_ < 4; ++i_) \
  _Pragma("unroll") for (int j_ = 0; j_ < 2; ++j_) { \
    acc[(mh)*4+i_][(nh)*2+j_] = __builtin_amdgcn_mfma_f32_16x16x32_bf16( \
        a[i_][0], bb[j_][0], acc[(mh)*4+i_][(nh)*2+j_], 0, 0, 0); \
    acc[(mh)*4+i_][(nh)*2+j_] = __builtin_amdgcn_mfma_f32_16x16x32_bf16( \
        a[i_][1], bb[j_][1], acc[(mh)*4+i_][(nh)*2+j_], 0, 0, 0); \
  } } while (0)

template <int MODE>
__global__ __launch_bounds__(512, 2) void gemm8p_k(
    const unsigned short* __restrict__ A, const unsigned short* __restrict__ BT, const int K,
    const float* __restrict__ e0, const float* __restrict__ e1,
    const float* __restrict__ e2, const float* __restrict__ e3,
    unsigned short* __restrict__ obf, float* __restrict__ ofl) {
  __shared__ unsigned short sA[2][16384];
  __shared__ unsigned short sB[2][16384];

  constexpr int GX = (MODE == 2) ? 1 : 4;
  constexpr int GY = (MODE == 2) ? 512 : 8;
  constexpr int NWG = GX * GY * ((MODE == 2) ? 1 : 64);

  const int tid = threadIdx.x;
  const int lane = tid & 63;
  const int wid = tid >> 6;
  const int wm = wid >> 2, wn = wid & 3;
  const int l15 = lane & 15, l4 = lane >> 4;
  const int wm64 = wm << 6, wn32 = wn << 5;

  // T1: bijective XCD swizzle (NWG % 8 == 0 for all modes)
  const int rbid = blockIdx.x + GX * (blockIdx.y + GY * blockIdx.z);
  const int bid = (rbid & 7) * (NWG >> 3) + (rbid >> 3);
  const int bx = bid % GX;
  const int by = (bid / GX) % GY;
  const int c = bid / (GX * GY);

  const int n0 = bx << 8;
  const int m0 = by << 8;

  const unsigned short* Ab = A;
  const unsigned short* Bb;
  if constexpr (MODE == 2) Bb = BT;
  else                     Bb = BT + ((size_t)c << 20);

  // staging geometry: slot s holds source 16B-chunk (row=s>>3, cc=(s&7)^(row&7))
  int rloc[2], csrc[2], chnk[2];
  const unsigned short* Asrc[2];
  const unsigned short* Bsrc[2];
#pragma unroll
  for (int q = 0; q < 2; ++q) {
    const int s = ((wid << 1) + q) * 64 + lane;
    rloc[q] = s >> 3;
    csrc[q] = ((s & 7) ^ ((s >> 3) & 7)) << 3;
    chnk[q] = ((wid << 1) + q) << 9;
    Asrc[q] = Ab + (size_t)(m0 + rloc[q]) * K + csrc[q];
    Bsrc[q] = Bb + (size_t)(n0 + rloc[q]) * K + csrc[q];
  }

  // swizzled ds_read col-chunk offsets (in ushorts)
  const int xorv = l15 & 7;
  const int ccx0 = (l4 ^ xorv) << 3;
  const int ccx1 = ((4 + l4) ^ xorv) << 3;

  f32x4 acc[8][4];
#pragma unroll
  for (int i = 0; i < 8; ++i)
#pragma unroll
    for (int j = 0; j < 4; ++j) acc[i][j] = (f32x4)(0.f);

  bf16x8 a[4][2], b0[2][2], b1[2][2];

  const int nt = K >> 6;  // 16

  // prologue: stage tile 0, drain, barrier
  STAGEA(0, 0, 0); STAGEB(0, 0, 0); STAGEB(1, 0, 0); STAGEA(1, 0, 0);
  VM0();
  BAR();

  for (int t = 0; t < nt - 1; ++t) {
    const int cb = t & 1, nb = cb ^ 1;
    // ---- P0 ----
    LOADA(0, cb);
    LOADB(0, b0, cb);
    STAGEA(0, t + 1, nb);
    BAR();
    LGKM0();
    __builtin_amdgcn_s_setprio(1);
    MMAQ(0, 0, b0);
    __builtin_amdgcn_s_setprio(0);
    VM4();
    BAR();
    // ---- P1 ----
    LOADB(1, b1, cb);
    STAGEB(0, t + 1, nb);
    BAR();
    LGKM0();
    __builtin_amdgcn_s_setprio(1);
    MMAQ(0, 1, b1);
    __builtin_amdgcn_s_setprio(0);
    VM4();
    BAR();
    // ---- P2 ----
    LOADA(1, cb);
    STAGEB(1, t + 1, nb);
    BAR();
    LGKM0();
    __builtin_amdgcn_s_setprio(1);
    MMAQ(1, 1, b1);
    __builtin_amdgcn_s_setprio(0);
    BAR();
    // ---- P3 ----
    STAGEA(1, t + 1, nb);
    BAR();
    __builtin_amdgcn_s_setprio(1);
    MMAQ(1, 0, b0);
    __builtin_amdgcn_s_setprio(0);
    VM4();
    BAR();
  }

  // ---- final tile (race-safe: full drain; no further staging) ----
  {
    const int cb = (nt - 1) & 1;  // = 1 for K=1024
    VM0();
    BAR();
    LOADA(0, cb);
    LOADB(0, b0, cb);
    LGKM0();
    __builtin_amdgcn_s_setprio(1);
    MMAQ(0, 0, b0);
    __builtin_amdgcn_s_setprio(0);
    LOADB(1, b1, cb);
    LGKM0();
    __builtin_amdgcn_s_setprio(1);
    MMAQ(0, 1, b1);
    __builtin_amdgcn_s_setprio(0);
    LOADA(1, cb);
    LGKM0();
    __builtin_amdgcn_s_setprio(1);
    MMAQ(1, 1, b1);
    MMAQ(1, 0, b0);
    __builtin_amdgcn_s_setprio(0);
  }

  // ---- epilogue ----
  int coln[2][2];
#pragma unroll
  for (int nh = 0; nh < 2; ++nh)
#pragma unroll
    for (int j = 0; j < 2; ++j) coln[nh][j] = n0 + nh * 128 + wn32 + j * 16 + l15;

  if constexpr (MODE == 0) {
    // fused scorer: s_partial[row] = sum over this block's 256 cols of relu(h)*w2
    float bias[2][2], w2v[2][2];
#pragma unroll
    for (int nh = 0; nh < 2; ++nh)
#pragma unroll
      for (int j = 0; j < 2; ++j) {
        bias[nh][j] = e0[(c << 10) + coln[nh][j]];
        w2v[nh][j]  = e1[(c << 10) + coln[nh][j]];
      }
    float* partL = (float*)&sA[0][0];  // 8 waves x 128 rows (4 KB); safe: final tile used buf 1
#pragma unroll
    for (int mh = 0; mh < 2; ++mh)
#pragma unroll
      for (int i = 0; i < 4; ++i)
#pragma unroll
        for (int rr = 0; rr < 4; ++rr) {
          float s = 0.f;
#pragma unroll
          for (int nh = 0; nh < 2; ++nh)
#pragma unroll
            for (int j = 0; j < 2; ++j) {
              float v = fmaxf(acc[mh * 4 + i][nh * 2 + j][rr] + bias[nh][j], 0.f);
              s += v * w2v[nh][j];
            }
          s += __shfl_xor(s, 1); s += __shfl_xor(s, 2);
          s += __shfl_xor(s, 4); s += __shfl_xor(s, 8);
          if (l15 == 0) partL[wid * 128 + mh * 64 + i * 16 + (l4 << 2) + rr] = s;
        }
    __syncthreads();
    if (tid < 256) {
      const int r = tid;
      const int mh_ = r >> 7, wmr = (r >> 6) & 1, low = r & 63;
      float s2 = 0.f;
#pragma unroll
      for (int wn2 = 0; wn2 < 4; ++wn2) s2 += partL[(wmr * 4 + wn2) * 128 + mh_ * 64 + low];
      ofl[(((size_t)(bx << 6) + c) << 11) + m0 + r] = s2;
    }
  } else if constexpr (MODE == 1) {
    float wl4[2][2], bb4[2][2];
#pragma unroll
    for (int nh = 0; nh < 2; ++nh)
#pragma unroll
      for (int j = 0; j < 2; ++j) {
        wl4[nh][j] = e0[(c << 10) + coln[nh][j]];
        bb4[nh][j] = e1[(c << 10) + coln[nh][j]];
      }
#pragma unroll
    for (int mh = 0; mh < 2; ++mh)
#pragma unroll
      for (int i = 0; i < 4; ++i)
#pragma unroll
        for (int rr = 0; rr < 4; ++rr) {
          const int row = m0 + mh * 128 + wm64 + i * 16 + (l4 << 2) + rr;  // = b
          const float cp = e2[((size_t)row << 6) + c];
          unsigned short* orow = obf + (((size_t)(c << 11) + row) << 10);
#pragma unroll
          for (int nh = 0; nh < 2; ++nh)
#pragma unroll
            for (int j = 0; j < 2; ++j) {
              float v = acc[mh * 4 + i][nh * 2 + j][rr] + cp * wl4[nh][j] + bb4[nh][j];
              orow[coln[nh][j]] = f2bf(fmaxf(v, 0.f));
            }
        }
  } else {
    float bias[2][2], wh[2][2];
#pragma unroll
    for (int nh = 0; nh < 2; ++nh)
#pragma unroll
      for (int j = 0; j < 2; ++j) {
        bias[nh][j] = (nh == 0) ? e0[coln[0][j]] : e1[coln[1][j] - 128];
        wh[nh][j]   = e3[coln[nh][j]];
      }
#pragma unroll
    for (int mh = 0; mh < 2; ++mh)
#pragma unroll
      for (int i = 0; i < 4; ++i)
#pragma unroll
        for (int rr = 0; rr < 4; ++rr) {
          const int rid = m0 + mh * 128 + wm64 + i * 16 + (l4 << 2) + rr;  // c*B + b
          const int cc = rid >> 11, b = rid & 2047;
          const float ev = e2[rid];  // e1024[c][b]
          const size_t ib = (((size_t)b << 6) + cc) << 7;
#pragma unroll
          for (int j = 0; j < 2; ++j) {  // nh=0 -> mu & ce
            float v = acc[mh * 4 + i][j][rr] + bias[0][j] + ev * wh[0][j];
            ofl[OFF_MU + ib + coln[0][j]] = v;
            ofl[OFF_CE + ib + coln[0][j]] = v;
          }
#pragma unroll
          for (int j = 0; j < 2; ++j) {  // nh=1 -> logvar
            float v = acc[mh * 4 + i][2 + j][rr] + bias[1][j] + ev * wh[1][j];
            ofl[OFF_LV + ib + (coln[1][j] - 128)] = v;
          }
        }
  }
}

// ---------------- launcher ----------------

extern "C" void kernel_launch(void* const* d_in, const int* in_sizes, int n_in,
                              void* d_out, int out_size, void* d_ws, size_t ws_size,
                              hipStream_t stream) {
  const float* x   = (const float*)d_in[0];
  const float* W1  = (const float*)d_in[2];
  const float* b1  = (const float*)d_in[3];
  const float* w2  = (const float*)d_in[4];
  const float* b2  = (const float*)d_in[5];
  const float* Wl  = (const float*)d_in[6];
  const float* bl  = (const float*)d_in[7];
  const float* Wmu = (const float*)d_in[8];
  const float* bmu = (const float*)d_in[9];
  const float* Wlv = (const float*)d_in[10];
  const float* blv = (const float*)d_in[11];
  float* out = (float*)d_out;

  char* ws = (char*)d_ws;
  unsigned short* xb     = (unsigned short*)(ws);                  //   4,194,304
  unsigned short* WT     = (unsigned short*)(ws + 4194304ull);     // 134,217,728 (W1T, later WlT)
  float* wlastf          = (float*)(ws + 138412032ull);            //     262,144
  float* blpf            = (float*)(ws + 138674176ull);            //     262,144
  float* Wlcolf          = (float*)(ws + 138936320ull);            //     262,144
  float* w2l             = (float*)(ws + 139198464ull);            //         256
  float* bl1024          = (float*)(ws + 139198720ull);            //         256
  unsigned short* WheadT = (unsigned short*)(ws + 139198976ull);   //     524,288
  float* whead1024f      = (float*)(ws + 139723264ull);            //       1,024
  float* presum          = (float*)(ws + 139724288ull);            //     524,288
  float* spart           = (float*)(ws + 140248576ull);            //   2,097,152 [4][C][B]
  float* cpf             = (float*)(ws + 142345728ull);            //     524,288
  float* e1024f          = (float*)(ws + 142870016ull);            //     524,288
  unsigned short* emb    = (unsigned short*)(ws + 143394304ull);   // 268,435,456 [C][B][1024]
  // total: 411,829,760 bytes

  convert_x_k<<<1024, 256, 0, stream>>>(x, xb);
  transpose_w1_k<<<dim3(32, 32, 64), dim3(32, 8), 0, stream>>>(W1, WT);
  prep_wl_k<<<256, 256, 0, stream>>>(Wl, bl, wlastf, blpf, Wlcolf, w2l, bl1024);
  convert_whead_k<<<1024, 256, 0, stream>>>(Wmu, Wlv, WheadT, whead1024f);
  colgemv_k<<<64, 256, 0, stream>>>(xb, Wlcolf, presum);
  gemm8p_k<0><<<dim3(4, 8, 64), 512, 0, stream>>>(xb, WT, 1024, b1, w2, nullptr, nullptr,
                                                  nullptr, spart);
  sigmoid_k<<<512, 256, 0, stream>>>(spart, b2, presum, w2l, bl1024, out, cpf, e1024f);
  transpose_wl_k<<<dim3(32, 32, 64), dim3(32, 8), 0, stream>>>(Wl, WT);
  gemm8p_k<1><<<dim3(4, 8, 64), 512, 0, stream>>>(xb, WT, 1024, wlastf, blpf, cpf, nullptr,
                                                  emb, nullptr);
  gemm8p_k<2><<<dim3(1, 512, 1), 512, 0, stream>>>(emb, WheadT, 1024, bmu, blv, e1024f,
                                                   whead1024f, nullptr, out);
}